// Round 6
// baseline (251.750 us; speedup 1.0000x reference)
//
#include <hip/hip_runtime.h>
#include <math.h>

#define BATCH 8
#define T 2048
#define H 1024
#define D 64

typedef __attribute__((ext_vector_type(8))) short bf16x8;
typedef __attribute__((ext_vector_type(4))) short bf16x4;
typedef __attribute__((ext_vector_type(4))) float f32x4;

// Scalar conversion (RNE), kept for prep_w.
__device__ __forceinline__ short f2bf(float f) {
  union { float f; unsigned u; } x; x.f = f;
  return (short)((x.u + 0x7FFFu + ((x.u >> 16) & 1u)) >> 16);
}

// Pair conversion, BIT-EXACT RNE (same math as f2bf), packed with v_perm.
// NOTE: v_cvt_pk_bf16_f32 is NOT used: it rounds toward zero (pkrtz
// heritage); the downward bias compounded to absmax 0.123 in round 1.
__device__ __forceinline__ unsigned cvt2(float lo, float hi) {
  union { float f; unsigned u; } a, b;
  a.f = lo; b.f = hi;
  unsigned ul = a.u + 0x7FFFu + ((a.u >> 16) & 1u);
  unsigned uh = b.u + 0x7FFFu + ((b.u >> 16) & 1u);
#if __has_builtin(__builtin_amdgcn_perm)
  return __builtin_amdgcn_perm(uh, ul, 0x07060302u);  // [ul.b2,ul.b3,uh.b2,uh.b3]
#else
  return (uh & 0xFFFF0000u) | (ul >> 16);
#endif
}

#if __has_builtin(__builtin_amdgcn_exp2f)
#define EXP2(x) __builtin_amdgcn_exp2f(x)
#else
#define EXP2(x) exp2f(x)
#endif

#define MFMA(a, b, c) __builtin_amdgcn_mfma_f32_16x16x32_bf16(a, b, c, 0, 0, 0)

#if __has_builtin(__builtin_amdgcn_mfma_f32_16x16x16bf16_1k)
#define MFMA16(a, b, c) __builtin_amdgcn_mfma_f32_16x16x16bf16_1k(a, b, c, 0, 0, 0)
#define HAVE_MFMA16 1
#elif __has_builtin(__builtin_amdgcn_mfma_f32_16x16x16_bf16)
#define MFMA16(a, b, c) __builtin_amdgcn_mfma_f32_16x16x16_bf16(a, b, c, 0, 0, 0)
#define HAVE_MFMA16 1
#else
#define HAVE_MFMA16 0
#endif

#define CH 6          // k-tiles per split-K chunk (384 keys)
#define NCHUNK_MAX 6  // ceil(32/CH)

// ---------------------------------------------------------------------------
// Kernel 1: W [1024][64] fp32 -> Wt[3][64 n][1024 k] bf16 (transposed).
// which 0 = Wq (pre-scaled by 0.125*log2e so attention uses exp2 directly).
// Block (0,0) additionally zeroes the 256 split-K arrival counters
// (workspace is POISONED, not zeroed, before each timed iteration).
// ---------------------------------------------------------------------------
__global__ __launch_bounds__(256) void prep_w(
    const float* __restrict__ Wq, const float* __restrict__ Wk,
    const float* __restrict__ Wv, short* __restrict__ Wt, int* __restrict__ cnt) {
  if (blockIdx.x == 0 && blockIdx.y == 0) cnt[threadIdx.x] = 0;
  const int which = blockIdx.y;
  const float* W = which == 0 ? Wq : which == 1 ? Wk : Wv;
  const float scale = which == 0 ? 0.125f * 1.44269504088896340736f : 1.0f;
  const int kbase = blockIdx.x * 64;
  const int n = threadIdx.x & 63;
  const int k0 = threadIdx.x >> 6;
  short* dst = Wt + (size_t)which * (D * H);
#pragma unroll
  for (int i = 0; i < 16; ++i) {
    int k = kbase + i * 4 + k0;
    dst[n * H + k] = f2bf(W[(size_t)k * D + n] * scale);
  }
}

// ---------------------------------------------------------------------------
// Kernel 2: fused q/k/v projection GEMM, 32-row M-tile, grid 512 (2 blk/CU).
// Wave tile = 32 rows x 48 cols; register-prefetch double buffering.
// ---------------------------------------------------------------------------
__global__ __launch_bounds__(256) void proj_mfma(
    const float* __restrict__ x, const short* __restrict__ Wt,
    short* __restrict__ qb, short* __restrict__ kb, short* __restrict__ vT) {
  __shared__ short As[32][72];
  __shared__ short Bs[3][64][72];
  const int mbase = blockIdx.x * 32;
  const int tid = threadIdx.x;
  const int lane = tid & 63, wv = tid >> 6;
  const int l15 = lane & 15, quad = lane >> 4;
  const int ra = tid >> 3, ca = (tid & 7) * 8;
  const int rb = tid >> 2, cb = (tid & 3) * 16;

  const float4* xsrc = (const float4*)(x + (size_t)(mbase + ra) * H + ca);
  float4 xr0 = xsrc[0], xr1 = xsrc[1];
  bf16x8 wr[3][2];
#pragma unroll
  for (int w3 = 0; w3 < 3; ++w3) {
    const bf16x8* s2 = (const bf16x8*)(Wt + (size_t)w3 * (D * H) + (size_t)rb * H + cb);
    wr[w3][0] = s2[0];
    wr[w3][1] = s2[1];
  }

  f32x4 acc[2][3] = {};  // [m-tile][n-tile]

  for (int k0 = 0; k0 < H; k0 += 64) {
    if (k0) __syncthreads();
    {
      union { unsigned u[4]; bf16x8 v; } p0;
      p0.u[0] = cvt2(xr0.x, xr0.y); p0.u[1] = cvt2(xr0.z, xr0.w);
      p0.u[2] = cvt2(xr1.x, xr1.y); p0.u[3] = cvt2(xr1.z, xr1.w);
      *(bf16x8*)&As[ra][ca] = p0.v;
#pragma unroll
      for (int w3 = 0; w3 < 3; ++w3) {
        *(bf16x8*)&Bs[w3][rb][cb] = wr[w3][0];
        *(bf16x8*)&Bs[w3][rb][cb + 8] = wr[w3][1];
      }
    }
    if (k0 + 64 < H) {  // prefetch next k-tile into regs (overlaps MFMA below)
      const float4* xs = xsrc + (size_t)((k0 >> 6) + 1) * 16;
      xr0 = xs[0]; xr1 = xs[1];
#pragma unroll
      for (int w3 = 0; w3 < 3; ++w3) {
        const bf16x8* s2 =
            (const bf16x8*)(Wt + (size_t)w3 * (D * H) + (size_t)rb * H + k0 + 64 + cb);
        wr[w3][0] = s2[0];
        wr[w3][1] = s2[1];
      }
    }
    __syncthreads();
#pragma unroll
    for (int kk = 0; kk < 2; ++kk) {
      bf16x8 a[2];
#pragma unroll
      for (int mt = 0; mt < 2; ++mt)
        a[mt] = *(const bf16x8*)&As[mt * 16 + l15][kk * 32 + quad * 8];
#pragma unroll
      for (int nt = 0; nt < 3; ++nt) {
        const int gnt = wv * 3 + nt;
        bf16x8 b = *(const bf16x8*)&Bs[gnt >> 2][(gnt & 3) * 16 + l15][kk * 32 + quad * 8];
#pragma unroll
        for (int mt = 0; mt < 2; ++mt) acc[mt][nt] = MFMA(a[mt], b, acc[mt][nt]);
      }
    }
  }

  // epilogue: row = mbase + mt*16 + quad*4 + r; col tile gnt = wv*3+nt
#pragma unroll
  for (int nt = 0; nt < 3; ++nt) {
    const int gnt = wv * 3 + nt;
    const int w3 = gnt >> 2;
    const int d = (gnt & 3) * 16 + l15;
#pragma unroll
    for (int mt = 0; mt < 2; ++mt) {
      const int row0 = mbase + mt * 16 + quad * 4;
      const unsigned u01 = cvt2(acc[mt][nt][0], acc[mt][nt][1]);
      const unsigned u23 = cvt2(acc[mt][nt][2], acc[mt][nt][3]);
      if (w3 < 2) {
        short* dst = (w3 == 0) ? qb : kb;
        dst[(size_t)(row0 + 0) * D + d] = (short)(u01 & 0xFFFFu);
        dst[(size_t)(row0 + 1) * D + d] = (short)(u01 >> 16);
        dst[(size_t)(row0 + 2) * D + d] = (short)(u23 & 0xFFFFu);
        dst[(size_t)(row0 + 3) * D + d] = (short)(u23 >> 16);
      } else {
        const int bb = row0 >> 11, t0 = row0 & 2047;
        *(int2*)(vT + ((size_t)(bb * D + d)) * T + t0) = make_int2((int)u01, (int)u23);
      }
    }
  }
}

// ---------------------------------------------------------------------------
// Kernel 3: transposed flash attention, split-K with INLINE combine.
// Chunk = CH=6 k-tiles (384 keys), staged in 3-tile groups. Multi-chunk
// (b,qt) rows: each chunk writes partials, releases with __threadfence,
// atomicAdd's an arrival counter; the LAST-arriving chunk acquires and
// reduces all partials (L2/L3-hot, overlaps with other blocks' tails).
// No spin, no dispatch-order assumption (Guideline 16 pattern).
// mode 1: grid 816 (8 b x 102 (qt,chunk)); mode 0: fallback, grid 256.
// ---------------------------------------------------------------------------
__global__ __launch_bounds__(256) void attn_mfma(
    const short* __restrict__ qbuf, const short* __restrict__ kbuf,
    const short* __restrict__ vT, float* __restrict__ out,
    float* __restrict__ Opart, float* __restrict__ lpart,
    int* __restrict__ cnt, int mode) {
  __shared__ short Ks[192][72];   // 27648 B
  __shared__ short Vs[64][200];   // 25600 B  (total 53248 < 64 KB static cap)
  __shared__ int s_old;

  const int g = blockIdx.x;
  int b, qt, c;
  if (mode == 0) {
    b = g >> 5; qt = g & 31; c = 0;
  } else {
    b = g / 102;
    int r = g - b * 102;
    qt = 0; c = 0;
    // qt-groups of 6 (gg = qt/6): gg<5 -> 6 qts x (gg+1) chunks; gg=5 -> 2 x 6
    for (int gg = 0;; ++gg) {
      const int cnt6 = (gg < 5) ? 6 * (gg + 1) : 12;
      if (r < cnt6) { qt = 6 * gg + r / (gg + 1); c = r - (r / (gg + 1)) * (gg + 1); break; }
      r -= cnt6;
    }
  }
  const int kt0 = c * CH;
  const int kt1 = (mode == 0) ? (qt + 1) : min(kt0 + CH, qt + 1);

  const int tid = threadIdx.x;
  const int lane = tid & 63, wv = tid >> 6;
  const int l15 = lane & 15, quad = lane >> 4;
  const int qrow = qt * 64 + wv * 16 + l15;

  const short* qp = qbuf + (size_t)(b * T + qrow) * D;
  bf16x8 qf0 = *(const bf16x8*)(qp + quad * 8);
  bf16x8 qf1 = *(const bf16x8*)(qp + 32 + quad * 8);

  const int srow = tid >> 2, soff = (tid & 3) * 16;
  const short* kbb = kbuf + (size_t)b * T * D;
  const short* vbb = vT + (size_t)b * D * T;

  f32x4 o[4] = {};
  f32x4 lsum4 = {};

  for (int base = kt0; base < kt1; base += 3) {
    const int nt3 = min(3, kt1 - base);
    if (base > kt0) __syncthreads();  // prev 3-tile group fully consumed
    for (int t3 = 0; t3 < nt3; ++t3) {
      const bf16x8* kp = (const bf16x8*)(kbb + (size_t)((base + t3) * 64 + srow) * D + soff);
      bf16x8 k0 = kp[0], k1 = kp[1];
      const bf16x8* vp = (const bf16x8*)(vbb + (size_t)srow * T + (base + t3) * 64 + soff);
      bf16x8 v0 = vp[0], v1 = vp[1];
      *(bf16x8*)&Ks[t3 * 64 + srow][soff] = k0;
      *(bf16x8*)&Ks[t3 * 64 + srow][soff + 8] = k1;
      *(bf16x8*)&Vs[srow][t3 * 64 + soff] = v0;
      *(bf16x8*)&Vs[srow][t3 * 64 + soff + 8] = v1;
    }
    __syncthreads();

    for (int tt = 0; tt < nt3; ++tt) {
      const int kt = base + tt;
      // S^T = K Q^T (log2 domain: q pre-scaled by 0.125*log2e)
      f32x4 s[4] = {};
#pragma unroll
      for (int nt = 0; nt < 4; ++nt) {
        bf16x8 ka0 = *(const bf16x8*)&Ks[tt * 64 + nt * 16 + l15][quad * 8];
        bf16x8 ka1 = *(const bf16x8*)&Ks[tt * 64 + nt * 16 + l15][32 + quad * 8];
        s[nt] = MFMA(ka1, qf1, MFMA(ka0, qf0, s[nt]));
      }
      const bool diag = (kt == qt);
#pragma unroll
      for (int nt = 0; nt < 4; ++nt) {
#pragma unroll
        for (int r = 0; r < 4; ++r) {
          float p = EXP2(s[nt][r]);
          if (diag) {
            int key = kt * 64 + nt * 16 + quad * 4 + r;
            if (key > qrow) p = 0.f;
          }
          s[nt][r] = p;
        }
        lsum4 += s[nt];
      }
#if HAVE_MFMA16
      // P^T already sits in the 16x16x16 B-operand layout: pack and go.
#pragma unroll
      for (int nt = 0; nt < 4; ++nt) {
        union { unsigned u[2]; bf16x4 v; } pb;
        pb.u[0] = cvt2(s[nt][0], s[nt][1]);
        pb.u[1] = cvt2(s[nt][2], s[nt][3]);
#pragma unroll
        for (int dt = 0; dt < 4; ++dt) {
          bf16x4 va = *(const bf16x4*)&Vs[dt * 16 + l15][tt * 64 + nt * 16 + quad * 4];
          o[dt] = MFMA16(va, pb.v, o[dt]);
        }
      }
#else
      // In-wave shuffle gather of 16x16x32 B-frags (verified earlier).
#pragma unroll
      for (int h = 0; h < 2; ++h) {
        int a01 = (int)cvt2(s[2 * h][0], s[2 * h][1]);
        int a23 = (int)cvt2(s[2 * h][2], s[2 * h][3]);
        int b01 = (int)cvt2(s[2 * h + 1][0], s[2 * h + 1][1]);
        int b23 = (int)cvt2(s[2 * h + 1][2], s[2 * h + 1][3]);
        const int srcA = l15 + ((quad & 1) << 5);
        const int srcB = srcA + 16;
        int gA01 = __shfl(a01, srcA), gA01b = __shfl(b01, srcA);
        int gA23 = __shfl(a23, srcA), gA23b = __shfl(b23, srcA);
        int gB01 = __shfl(a01, srcB), gB01b = __shfl(b01, srcB);
        int gB23 = __shfl(a23, srcB), gB23b = __shfl(b23, srcB);
        union { int d[4]; bf16x8 v; } pf;
        const bool lo = (quad < 2);
        pf.d[0] = lo ? gA01 : gA01b;
        pf.d[1] = lo ? gA23 : gA23b;
        pf.d[2] = lo ? gB01 : gB01b;
        pf.d[3] = lo ? gB23 : gB23b;
#pragma unroll
        for (int dt = 0; dt < 4; ++dt) {
          bf16x8 va = *(const bf16x8*)&Vs[dt * 16 + l15][tt * 64 + h * 32 + quad * 8];
          o[dt] = MFMA(va, pf.v, o[dt]);
        }
      }
#endif
    }
  }

  float lv = (lsum4[0] + lsum4[1]) + (lsum4[2] + lsum4[3]);
  lv += __shfl_xor(lv, 16);
  lv += __shfl_xor(lv, 32);

  if (kt0 == 0 && kt1 == qt + 1) {  // sole chunk: normalize, write out
    const float inv = 1.0f / lv;
    float* op = out + (size_t)(b * T + qrow) * D;
#pragma unroll
    for (int dt = 0; dt < 4; ++dt)
      *(float4*)(op + dt * 16 + quad * 4) =
          make_float4(o[dt][0] * inv, o[dt][1] * inv, o[dt][2] * inv, o[dt][3] * inv);
  } else {
    const int prow = b * T + qrow;
    float* pp = Opart + ((size_t)c * 16384 + prow) * D;
#pragma unroll
    for (int dt = 0; dt < 4; ++dt)
      *(float4*)(pp + dt * 16 + quad * 4) =
          make_float4(o[dt][0], o[dt][1], o[dt][2], o[dt][3]);
    if (quad == 0) lpart[c * 16384 + prow] = lv;

    // ---- inline combine: last-arriving chunk reduces all partials ----
    const int nc = qt / CH + 1;              // chunks for this (b,qt), >= 2
    __syncthreads();                         // all partial stores issued
    __threadfence();                         // release to device scope
    if (tid == 0) s_old = atomicAdd(&cnt[b * 32 + qt], 1);
    __syncthreads();
    if (s_old == nc - 1) {                   // we are last: do the combine
      __threadfence();                       // acquire
      const int row = tid >> 2;
      const int d4 = (tid & 3) * 16;
      const int prow2 = b * T + qt * 64 + row;
      f32x4 ac[4] = {};
      float l = 0.f;
      for (int cc = 0; cc < nc; ++cc) {
        const float* pq = Opart + ((size_t)cc * 16384 + prow2) * D + d4;
#pragma unroll
        for (int j = 0; j < 4; ++j) {
          const float4 t = *(const float4*)(pq + j * 4);
          ac[j][0] += t.x; ac[j][1] += t.y; ac[j][2] += t.z; ac[j][3] += t.w;
        }
        l += lpart[cc * 16384 + prow2];
      }
      const float inv = 1.0f / l;
      float* op = out + (size_t)prow2 * D + d4;
#pragma unroll
      for (int j = 0; j < 4; ++j)
        *(float4*)(op + j * 4) =
            make_float4(ac[j][0] * inv, ac[j][1] * inv, ac[j][2] * inv, ac[j][3] * inv);
    }
  }
}

// ---------------------------------------------------------------------------
extern "C" void kernel_launch(void* const* d_in, const int* in_sizes, int n_in,
                              void* d_out, int out_size, void* d_ws, size_t ws_size,
                              hipStream_t stream) {
  const float* x  = (const float*)d_in[0];
  const float* Wk = (const float*)d_in[1];
  const float* Wq = (const float*)d_in[2];
  const float* Wv = (const float*)d_in[3];
  float* out = (float*)d_out;

  const size_t M = (size_t)BATCH * T * D;  // 1,048,576 elements
  short* qb = (short*)d_ws;
  short* kb = qb + M;
  short* vT = kb + M;
  short* Wt = vT + M;                       // 196,608 shorts
  float* Opart = (float*)(Wt + 196608);
  float* lpart = Opart + (size_t)NCHUNK_MAX * 16384 * 64;
  int* cnt = (int*)(lpart + (size_t)NCHUNK_MAX * 16384);  // 256 ints

  const size_t need = (3 * M + 196608) * 2 +
                      ((size_t)NCHUNK_MAX * 16384 * 64 + (size_t)NCHUNK_MAX * 16384) * 4 +
                      1024;
  const bool split = ws_size >= need;

  prep_w<<<dim3(16, 3), 256, 0, stream>>>(Wq, Wk, Wv, Wt, cnt);
  proj_mfma<<<dim3(512), 256, 0, stream>>>(x, Wt, qb, kb, vT);
  if (split) {
    attn_mfma<<<dim3(816), 256, 0, stream>>>(qb, kb, vT, out, Opart, lpart, cnt, 1);
  } else {
    attn_mfma<<<dim3(256), 256, 0, stream>>>(qb, kb, vT, out, Opart, lpart, cnt, 0);
  }
}

// Round 7
// 141.647 us; speedup vs baseline: 1.7773x; 1.7773x over previous
//
#include <hip/hip_runtime.h>
#include <math.h>

#define BATCH 8
#define T 2048
#define H 1024
#define D 64

typedef __attribute__((ext_vector_type(8))) short bf16x8;
typedef __attribute__((ext_vector_type(4))) short bf16x4;
typedef __attribute__((ext_vector_type(4))) float f32x4;

// Scalar conversion (RNE), kept for prep_w.
__device__ __forceinline__ short f2bf(float f) {
  union { float f; unsigned u; } x; x.f = f;
  return (short)((x.u + 0x7FFFu + ((x.u >> 16) & 1u)) >> 16);
}

// Pair conversion, BIT-EXACT RNE (same math as f2bf), packed with v_perm.
// NOTE: v_cvt_pk_bf16_f32 is NOT used: it rounds toward zero (pkrtz
// heritage); the downward bias compounded to absmax 0.123 in round 1.
__device__ __forceinline__ unsigned cvt2(float lo, float hi) {
  union { float f; unsigned u; } a, b;
  a.f = lo; b.f = hi;
  unsigned ul = a.u + 0x7FFFu + ((a.u >> 16) & 1u);
  unsigned uh = b.u + 0x7FFFu + ((b.u >> 16) & 1u);
#if __has_builtin(__builtin_amdgcn_perm)
  return __builtin_amdgcn_perm(uh, ul, 0x07060302u);  // [ul.b2,ul.b3,uh.b2,uh.b3]
#else
  return (uh & 0xFFFF0000u) | (ul >> 16);
#endif
}

#if __has_builtin(__builtin_amdgcn_exp2f)
#define EXP2(x) __builtin_amdgcn_exp2f(x)
#else
#define EXP2(x) exp2f(x)
#endif

#define MFMA(a, b, c) __builtin_amdgcn_mfma_f32_16x16x32_bf16(a, b, c, 0, 0, 0)

#if __has_builtin(__builtin_amdgcn_mfma_f32_16x16x16bf16_1k)
#define MFMA16(a, b, c) __builtin_amdgcn_mfma_f32_16x16x16bf16_1k(a, b, c, 0, 0, 0)
#define HAVE_MFMA16 1
#elif __has_builtin(__builtin_amdgcn_mfma_f32_16x16x16_bf16)
#define MFMA16(a, b, c) __builtin_amdgcn_mfma_f32_16x16x16_bf16(a, b, c, 0, 0, 0)
#define HAVE_MFMA16 1
#else
#define HAVE_MFMA16 0
#endif

#define CH 6          // k-tiles per split-K chunk (384 keys)
#define NCHUNK_MAX 6  // ceil(32/CH)

// ---------------------------------------------------------------------------
// Kernel 1: W [1024][64] fp32 -> Wt[3][64 n][1024 k] bf16 (transposed).
// which 0 = Wq (pre-scaled by 0.125*log2e so attention uses exp2 directly).
// ---------------------------------------------------------------------------
__global__ __launch_bounds__(256) void prep_w(
    const float* __restrict__ Wq, const float* __restrict__ Wk,
    const float* __restrict__ Wv, short* __restrict__ Wt) {
  const int which = blockIdx.y;
  const float* W = which == 0 ? Wq : which == 1 ? Wk : Wv;
  const float scale = which == 0 ? 0.125f * 1.44269504088896340736f : 1.0f;
  const int kbase = blockIdx.x * 64;
  const int n = threadIdx.x & 63;
  const int k0 = threadIdx.x >> 6;
  short* dst = Wt + (size_t)which * (D * H);
#pragma unroll
  for (int i = 0; i < 16; ++i) {
    int k = kbase + i * 4 + k0;
    dst[n * H + k] = f2bf(W[(size_t)k * D + n] * scale);
  }
}

// ---------------------------------------------------------------------------
// Kernel 2: fused q/k/v projection GEMM, 64-row M-tile (round-3 verified).
// Wave tile = 64 rows x 48 cols; register-prefetch double buffering.
// ---------------------------------------------------------------------------
__global__ __launch_bounds__(256) void proj_mfma(
    const float* __restrict__ x, const short* __restrict__ Wt,
    short* __restrict__ qb, short* __restrict__ kb, short* __restrict__ vT) {
  __shared__ short As[64][72];
  __shared__ short Bs[3][64][72];
  const int mbase = blockIdx.x * 64;
  const int tid = threadIdx.x;
  const int lane = tid & 63, wv = tid >> 6;
  const int l15 = lane & 15, quad = lane >> 4;
  const int ra = tid >> 2, ca = (tid & 3) * 16;

  const float4* xsrc = (const float4*)(x + (size_t)(mbase + ra) * H + ca);
  float4 xr0 = xsrc[0], xr1 = xsrc[1], xr2 = xsrc[2], xr3 = xsrc[3];
  bf16x8 wr[3][2];
#pragma unroll
  for (int w3 = 0; w3 < 3; ++w3) {
    const bf16x8* s2 = (const bf16x8*)(Wt + (size_t)w3 * (D * H) + (size_t)ra * H + ca);
    wr[w3][0] = s2[0];
    wr[w3][1] = s2[1];
  }

  f32x4 acc[4][3] = {};  // [m-tile][n-tile]

  for (int k0 = 0; k0 < H; k0 += 64) {
    if (k0) __syncthreads();
    {
      union { unsigned u[4]; bf16x8 v; } p0, p1;
      p0.u[0] = cvt2(xr0.x, xr0.y); p0.u[1] = cvt2(xr0.z, xr0.w);
      p0.u[2] = cvt2(xr1.x, xr1.y); p0.u[3] = cvt2(xr1.z, xr1.w);
      p1.u[0] = cvt2(xr2.x, xr2.y); p1.u[1] = cvt2(xr2.z, xr2.w);
      p1.u[2] = cvt2(xr3.x, xr3.y); p1.u[3] = cvt2(xr3.z, xr3.w);
      *(bf16x8*)&As[ra][ca] = p0.v;
      *(bf16x8*)&As[ra][ca + 8] = p1.v;
#pragma unroll
      for (int w3 = 0; w3 < 3; ++w3) {
        *(bf16x8*)&Bs[w3][ra][ca] = wr[w3][0];
        *(bf16x8*)&Bs[w3][ra][ca + 8] = wr[w3][1];
      }
    }
    if (k0 + 64 < H) {  // prefetch next k-tile into regs (overlaps MFMA below)
      const float4* xs = xsrc + (size_t)((k0 >> 6) + 1) * 16;
      xr0 = xs[0]; xr1 = xs[1]; xr2 = xs[2]; xr3 = xs[3];
#pragma unroll
      for (int w3 = 0; w3 < 3; ++w3) {
        const bf16x8* s2 =
            (const bf16x8*)(Wt + (size_t)w3 * (D * H) + (size_t)ra * H + k0 + 64 + ca);
        wr[w3][0] = s2[0];
        wr[w3][1] = s2[1];
      }
    }
    __syncthreads();
#pragma unroll
    for (int kk = 0; kk < 2; ++kk) {
      bf16x8 a[4];
#pragma unroll
      for (int mt = 0; mt < 4; ++mt)
        a[mt] = *(const bf16x8*)&As[mt * 16 + l15][kk * 32 + quad * 8];
#pragma unroll
      for (int nt = 0; nt < 3; ++nt) {
        const int gnt = wv * 3 + nt;
        bf16x8 b = *(const bf16x8*)&Bs[gnt >> 2][(gnt & 3) * 16 + l15][kk * 32 + quad * 8];
#pragma unroll
        for (int mt = 0; mt < 4; ++mt) acc[mt][nt] = MFMA(a[mt], b, acc[mt][nt]);
      }
    }
  }

  // epilogue: row = mbase + mt*16 + quad*4 + r; col tile gnt = wv*3+nt
#pragma unroll
  for (int nt = 0; nt < 3; ++nt) {
    const int gnt = wv * 3 + nt;
    const int w3 = gnt >> 2;
    const int d = (gnt & 3) * 16 + l15;
#pragma unroll
    for (int mt = 0; mt < 4; ++mt) {
      const int row0 = mbase + mt * 16 + quad * 4;
      const unsigned u01 = cvt2(acc[mt][nt][0], acc[mt][nt][1]);
      const unsigned u23 = cvt2(acc[mt][nt][2], acc[mt][nt][3]);
      if (w3 < 2) {
        short* dst = (w3 == 0) ? qb : kb;
        dst[(size_t)(row0 + 0) * D + d] = (short)(u01 & 0xFFFFu);
        dst[(size_t)(row0 + 1) * D + d] = (short)(u01 >> 16);
        dst[(size_t)(row0 + 2) * D + d] = (short)(u23 & 0xFFFFu);
        dst[(size_t)(row0 + 3) * D + d] = (short)(u23 >> 16);
      } else {
        const int bb = row0 >> 11, t0 = row0 & 2047;
        *(int2*)(vT + ((size_t)(bb * D + d)) * T + t0) = make_int2((int)u01, (int)u23);
      }
    }
  }
}

// ---------------------------------------------------------------------------
// Kernel 3: transposed flash attention, split-K, register-staged K/V
// double buffering (T14 async-STAGE split): group g+1's 12 global loads
// are issued into registers BEFORE computing group g, so their L2/HBM
// latency hides under the MFMA+softmax of the current group. ds_writes
// happen between two barriers (same barrier count as before). All register
// indices static via unroll+predication (no scratch).
// mode 1: grid 816 (8 b x 102 (qt,chunk)); mode 0: fallback, grid 256.
// ---------------------------------------------------------------------------
__global__ __launch_bounds__(256) void attn_mfma(
    const short* __restrict__ qbuf, const short* __restrict__ kbuf,
    const short* __restrict__ vT, float* __restrict__ out,
    float* __restrict__ Opart, float* __restrict__ lpart, int mode) {
  __shared__ short Ks[192][72];   // 27648 B
  __shared__ short Vs[64][200];   // 25600 B  (total 53248 < 64 KB static cap)

  const int g = blockIdx.x;
  int b, qt, c;
  if (mode == 0) {
    b = g >> 5; qt = g & 31; c = 0;
  } else {
    b = g / 102;
    int r = g - b * 102;
    qt = 0; c = 0;
    // qt-groups of 6 (gg = qt/6): gg<5 -> 6 qts x (gg+1) chunks; gg=5 -> 2 x 6
    for (int gg = 0;; ++gg) {
      const int cnt = (gg < 5) ? 6 * (gg + 1) : 12;
      if (r < cnt) { qt = 6 * gg + r / (gg + 1); c = r - (r / (gg + 1)) * (gg + 1); break; }
      r -= cnt;
    }
  }
  const int kt0 = c * CH;
  const int kt1 = (mode == 0) ? (qt + 1) : min(kt0 + CH, qt + 1);

  const int tid = threadIdx.x;
  const int lane = tid & 63, wv = tid >> 6;
  const int l15 = lane & 15, quad = lane >> 4;
  const int qrow = qt * 64 + wv * 16 + l15;

  const short* qp = qbuf + (size_t)(b * T + qrow) * D;
  bf16x8 qf0 = *(const bf16x8*)(qp + quad * 8);
  bf16x8 qf1 = *(const bf16x8*)(qp + 32 + quad * 8);

  const int srow = tid >> 2, soff = (tid & 3) * 16;
  const short* kbb = kbuf + (size_t)b * T * D;
  const short* vbb = vT + (size_t)b * D * T;

  f32x4 o[4] = {};
  f32x4 lsum4 = {};

  // register staging buffers for one 3-tile group (static-indexed only)
  bf16x8 kr[3][2], vr[3][2];

  int base = kt0;
  int nt3 = min(3, kt1 - base);

  // prologue: load + commit group 0
#pragma unroll
  for (int t3 = 0; t3 < 3; ++t3)
    if (t3 < nt3) {
      const bf16x8* kp = (const bf16x8*)(kbb + (size_t)((base + t3) * 64 + srow) * D + soff);
      kr[t3][0] = kp[0]; kr[t3][1] = kp[1];
      const bf16x8* vp = (const bf16x8*)(vbb + (size_t)srow * T + (base + t3) * 64 + soff);
      vr[t3][0] = vp[0]; vr[t3][1] = vp[1];
    }
#pragma unroll
  for (int t3 = 0; t3 < 3; ++t3)
    if (t3 < nt3) {
      *(bf16x8*)&Ks[t3 * 64 + srow][soff] = kr[t3][0];
      *(bf16x8*)&Ks[t3 * 64 + srow][soff + 8] = kr[t3][1];
      *(bf16x8*)&Vs[srow][t3 * 64 + soff] = vr[t3][0];
      *(bf16x8*)&Vs[srow][t3 * 64 + soff + 8] = vr[t3][1];
    }
  __syncthreads();

  for (;;) {
    const int nbase = base + 3;
    const int nn3 = min(3, kt1 - nbase);
    if (nn3 > 0) {  // issue next group's loads early: hide under compute
#pragma unroll
      for (int t3 = 0; t3 < 3; ++t3)
        if (t3 < nn3) {
          const bf16x8* kp =
              (const bf16x8*)(kbb + (size_t)((nbase + t3) * 64 + srow) * D + soff);
          kr[t3][0] = kp[0]; kr[t3][1] = kp[1];
          const bf16x8* vp =
              (const bf16x8*)(vbb + (size_t)srow * T + (nbase + t3) * 64 + soff);
          vr[t3][0] = vp[0]; vr[t3][1] = vp[1];
        }
    }

    for (int tt = 0; tt < nt3; ++tt) {
      const int kt = base + tt;
      // S^T = K Q^T (log2 domain: q pre-scaled by 0.125*log2e)
      f32x4 s[4] = {};
#pragma unroll
      for (int nt = 0; nt < 4; ++nt) {
        bf16x8 ka0 = *(const bf16x8*)&Ks[tt * 64 + nt * 16 + l15][quad * 8];
        bf16x8 ka1 = *(const bf16x8*)&Ks[tt * 64 + nt * 16 + l15][32 + quad * 8];
        s[nt] = MFMA(ka1, qf1, MFMA(ka0, qf0, s[nt]));
      }
      const bool diag = (kt == qt);
#pragma unroll
      for (int nt = 0; nt < 4; ++nt) {
#pragma unroll
        for (int r = 0; r < 4; ++r) {
          float p = EXP2(s[nt][r]);
          if (diag) {
            int key = kt * 64 + nt * 16 + quad * 4 + r;
            if (key > qrow) p = 0.f;
          }
          s[nt][r] = p;
        }
        lsum4 += s[nt];
      }
#if HAVE_MFMA16
      // P^T already sits in the 16x16x16 B-operand layout: pack and go.
#pragma unroll
      for (int nt = 0; nt < 4; ++nt) {
        union { unsigned u[2]; bf16x4 v; } pb;
        pb.u[0] = cvt2(s[nt][0], s[nt][1]);
        pb.u[1] = cvt2(s[nt][2], s[nt][3]);
#pragma unroll
        for (int dt = 0; dt < 4; ++dt) {
          bf16x4 va = *(const bf16x4*)&Vs[dt * 16 + l15][tt * 64 + nt * 16 + quad * 4];
          o[dt] = MFMA16(va, pb.v, o[dt]);
        }
      }
#else
      // In-wave shuffle gather of 16x16x32 B-frags (verified earlier).
#pragma unroll
      for (int h = 0; h < 2; ++h) {
        int a01 = (int)cvt2(s[2 * h][0], s[2 * h][1]);
        int a23 = (int)cvt2(s[2 * h][2], s[2 * h][3]);
        int b01 = (int)cvt2(s[2 * h + 1][0], s[2 * h + 1][1]);
        int b23 = (int)cvt2(s[2 * h + 1][2], s[2 * h + 1][3]);
        const int srcA = l15 + ((quad & 1) << 5);
        const int srcB = srcA + 16;
        int gA01 = __shfl(a01, srcA), gA01b = __shfl(b01, srcA);
        int gA23 = __shfl(a23, srcA), gA23b = __shfl(b23, srcA);
        int gB01 = __shfl(a01, srcB), gB01b = __shfl(b01, srcB);
        int gB23 = __shfl(a23, srcB), gB23b = __shfl(b23, srcB);
        union { int d[4]; bf16x8 v; } pf;
        const bool lo = (quad < 2);
        pf.d[0] = lo ? gA01 : gA01b;
        pf.d[1] = lo ? gA23 : gA23b;
        pf.d[2] = lo ? gB01 : gB01b;
        pf.d[3] = lo ? gB23 : gB23b;
#pragma unroll
        for (int dt = 0; dt < 4; ++dt) {
          bf16x8 va = *(const bf16x8*)&Vs[dt * 16 + l15][tt * 64 + h * 32 + quad * 8];
          o[dt] = MFMA(va, pf.v, o[dt]);
        }
      }
#endif
    }

    if (nn3 <= 0) break;
    __syncthreads();  // all waves done reading current LDS group
#pragma unroll
    for (int t3 = 0; t3 < 3; ++t3)
      if (t3 < nn3) {
        *(bf16x8*)&Ks[t3 * 64 + srow][soff] = kr[t3][0];
        *(bf16x8*)&Ks[t3 * 64 + srow][soff + 8] = kr[t3][1];
        *(bf16x8*)&Vs[srow][t3 * 64 + soff] = vr[t3][0];
        *(bf16x8*)&Vs[srow][t3 * 64 + soff + 8] = vr[t3][1];
      }
    __syncthreads();  // new group visible
    base = nbase; nt3 = nn3;
  }

  float lv = (lsum4[0] + lsum4[1]) + (lsum4[2] + lsum4[3]);
  lv += __shfl_xor(lv, 16);
  lv += __shfl_xor(lv, 32);

  if (kt0 == 0 && kt1 == qt + 1) {  // sole chunk: normalize, write out
    const float inv = 1.0f / lv;
    float* op = out + (size_t)(b * T + qrow) * D;
#pragma unroll
    for (int dt = 0; dt < 4; ++dt)
      *(float4*)(op + dt * 16 + quad * 4) =
          make_float4(o[dt][0] * inv, o[dt][1] * inv, o[dt][2] * inv, o[dt][3] * inv);
  } else {
    const int prow = b * T + qrow;
    float* pp = Opart + ((size_t)c * 16384 + prow) * D;
#pragma unroll
    for (int dt = 0; dt < 4; ++dt)
      *(float4*)(pp + dt * 16 + quad * 4) =
          make_float4(o[dt][0], o[dt][1], o[dt][2], o[dt][3]);
    if (quad == 0) lpart[c * 16384 + prow] = lv;
  }
}

// ---------------------------------------------------------------------------
// Kernel 4: combine split-K partials for rows with >=2 chunks (qrow >= 384).
// ---------------------------------------------------------------------------
__global__ __launch_bounds__(256) void combine_k(
    const float* __restrict__ Opart, const float* __restrict__ lpart,
    float* __restrict__ out) {
  const int gid = blockIdx.x * 256 + threadIdx.x;  // 832*256 = 212992
  const int r16 = gid >> 4;                        // 0..13311
  const int b = r16 / 1664;
  const int qrow = 384 + (r16 - b * 1664);
  const int row = b * T + qrow;
  const int d4 = (gid & 15) << 2;
  const int nc = (qrow >> 6) / CH + 1;  // 2..6 chunks
  float a0 = 0.f, a1 = 0.f, a2 = 0.f, a3 = 0.f, l = 0.f;
  for (int c = 0; c < nc; ++c) {
    const float4 t = *(const float4*)(Opart + ((size_t)c * 16384 + row) * D + d4);
    a0 += t.x; a1 += t.y; a2 += t.z; a3 += t.w;
    l += lpart[c * 16384 + row];
  }
  const float inv = 1.0f / l;
  *(float4*)(out + (size_t)row * D + d4) = make_float4(a0 * inv, a1 * inv, a2 * inv, a3 * inv);
}

// ---------------------------------------------------------------------------
extern "C" void kernel_launch(void* const* d_in, const int* in_sizes, int n_in,
                              void* d_out, int out_size, void* d_ws, size_t ws_size,
                              hipStream_t stream) {
  const float* x  = (const float*)d_in[0];
  const float* Wk = (const float*)d_in[1];
  const float* Wq = (const float*)d_in[2];
  const float* Wv = (const float*)d_in[3];
  float* out = (float*)d_out;

  const size_t M = (size_t)BATCH * T * D;  // 1,048,576 elements
  short* qb = (short*)d_ws;
  short* kb = qb + M;
  short* vT = kb + M;
  short* Wt = vT + M;                       // 196,608 shorts
  float* Opart = (float*)(Wt + 196608);
  float* lpart = Opart + (size_t)NCHUNK_MAX * 16384 * 64;

  const size_t need = (3 * M + 196608) * 2 +
                      ((size_t)NCHUNK_MAX * 16384 * 64 + (size_t)NCHUNK_MAX * 16384) * 4;
  const bool split = ws_size >= need;

  prep_w<<<dim3(16, 3), 256, 0, stream>>>(Wq, Wk, Wv, Wt);
  proj_mfma<<<dim3(256), 256, 0, stream>>>(x, Wt, qb, kb, vT);
  if (split) {
    attn_mfma<<<dim3(816), 256, 0, stream>>>(qb, kb, vT, out, Opart, lpart, 1);
    combine_k<<<dim3(832), 256, 0, stream>>>(Opart, lpart, out);
  } else {
    attn_mfma<<<dim3(256), 256, 0, stream>>>(qb, kb, vT, out, Opart, lpart, 0);
  }
}

// Round 8
// 135.959 us; speedup vs baseline: 1.8517x; 1.0418x over previous
//
#include <hip/hip_runtime.h>
#include <math.h>

#define BATCH 8
#define T 2048
#define H 1024
#define D 64

typedef __attribute__((ext_vector_type(8))) short bf16x8;
typedef __attribute__((ext_vector_type(4))) short bf16x4;
typedef __attribute__((ext_vector_type(4))) float f32x4;

// Scalar conversion (RNE), kept for prep_w.
__device__ __forceinline__ short f2bf(float f) {
  union { float f; unsigned u; } x; x.f = f;
  return (short)((x.u + 0x7FFFu + ((x.u >> 16) & 1u)) >> 16);
}

// Pair conversion, BIT-EXACT RNE (same math as f2bf), packed with v_perm.
// NOTE: v_cvt_pk_bf16_f32 is NOT used: it rounds toward zero (pkrtz
// heritage); the downward bias compounded to absmax 0.123 in round 1.
__device__ __forceinline__ unsigned cvt2(float lo, float hi) {
  union { float f; unsigned u; } a, b;
  a.f = lo; b.f = hi;
  unsigned ul = a.u + 0x7FFFu + ((a.u >> 16) & 1u);
  unsigned uh = b.u + 0x7FFFu + ((b.u >> 16) & 1u);
#if __has_builtin(__builtin_amdgcn_perm)
  return __builtin_amdgcn_perm(uh, ul, 0x07060302u);  // [ul.b2,ul.b3,uh.b2,uh.b3]
#else
  return (uh & 0xFFFF0000u) | (ul >> 16);
#endif
}

#if __has_builtin(__builtin_amdgcn_exp2f)
#define EXP2(x) __builtin_amdgcn_exp2f(x)
#else
#define EXP2(x) exp2f(x)
#endif

#define MFMA(a, b, c) __builtin_amdgcn_mfma_f32_16x16x32_bf16(a, b, c, 0, 0, 0)

#if __has_builtin(__builtin_amdgcn_mfma_f32_16x16x16bf16_1k)
#define MFMA16(a, b, c) __builtin_amdgcn_mfma_f32_16x16x16bf16_1k(a, b, c, 0, 0, 0)
#define HAVE_MFMA16 1
#elif __has_builtin(__builtin_amdgcn_mfma_f32_16x16x16_bf16)
#define MFMA16(a, b, c) __builtin_amdgcn_mfma_f32_16x16x16_bf16(a, b, c, 0, 0, 0)
#define HAVE_MFMA16 1
#else
#define HAVE_MFMA16 0
#endif

// CH=8: attn grid = 8 b x 80 (qt,chunk) = 640 blocks <= 768 co-residency
// slots (53KB LDS -> 3 blocks/CU x 256 CU), so the whole attn kernel runs
// in ONE dispatch wave (CH=6's 816 blocks needed two). Also shrinks split-K
// partial traffic (max 4 chunks vs 6).
#define CH 8
#define NCHUNK_MAX 4  // ceil(32/CH)

// ---------------------------------------------------------------------------
// Kernel 1: W [1024][64] fp32 -> Wt[3][64 n][1024 k] bf16 (transposed).
// which 0 = Wq (pre-scaled by 0.125*log2e so attention uses exp2 directly).
// ---------------------------------------------------------------------------
__global__ __launch_bounds__(256) void prep_w(
    const float* __restrict__ Wq, const float* __restrict__ Wk,
    const float* __restrict__ Wv, short* __restrict__ Wt) {
  const int which = blockIdx.y;
  const float* W = which == 0 ? Wq : which == 1 ? Wk : Wv;
  const float scale = which == 0 ? 0.125f * 1.44269504088896340736f : 1.0f;
  const int kbase = blockIdx.x * 64;
  const int n = threadIdx.x & 63;
  const int k0 = threadIdx.x >> 6;
  short* dst = Wt + (size_t)which * (D * H);
#pragma unroll
  for (int i = 0; i < 16; ++i) {
    int k = kbase + i * 4 + k0;
    dst[n * H + k] = f2bf(W[(size_t)k * D + n] * scale);
  }
}

// ---------------------------------------------------------------------------
// Kernel 2: fused q/k/v projection GEMM, 64-row M-tile (round-3 verified).
// Wave tile = 64 rows x 48 cols; register-prefetch double buffering.
// ---------------------------------------------------------------------------
__global__ __launch_bounds__(256) void proj_mfma(
    const float* __restrict__ x, const short* __restrict__ Wt,
    short* __restrict__ qb, short* __restrict__ kb, short* __restrict__ vT) {
  __shared__ short As[64][72];
  __shared__ short Bs[3][64][72];
  const int mbase = blockIdx.x * 64;
  const int tid = threadIdx.x;
  const int lane = tid & 63, wv = tid >> 6;
  const int l15 = lane & 15, quad = lane >> 4;
  const int ra = tid >> 2, ca = (tid & 3) * 16;

  const float4* xsrc = (const float4*)(x + (size_t)(mbase + ra) * H + ca);
  float4 xr0 = xsrc[0], xr1 = xsrc[1], xr2 = xsrc[2], xr3 = xsrc[3];
  bf16x8 wr[3][2];
#pragma unroll
  for (int w3 = 0; w3 < 3; ++w3) {
    const bf16x8* s2 = (const bf16x8*)(Wt + (size_t)w3 * (D * H) + (size_t)ra * H + ca);
    wr[w3][0] = s2[0];
    wr[w3][1] = s2[1];
  }

  f32x4 acc[4][3] = {};  // [m-tile][n-tile]

  for (int k0 = 0; k0 < H; k0 += 64) {
    if (k0) __syncthreads();
    {
      union { unsigned u[4]; bf16x8 v; } p0, p1;
      p0.u[0] = cvt2(xr0.x, xr0.y); p0.u[1] = cvt2(xr0.z, xr0.w);
      p0.u[2] = cvt2(xr1.x, xr1.y); p0.u[3] = cvt2(xr1.z, xr1.w);
      p1.u[0] = cvt2(xr2.x, xr2.y); p1.u[1] = cvt2(xr2.z, xr2.w);
      p1.u[2] = cvt2(xr3.x, xr3.y); p1.u[3] = cvt2(xr3.z, xr3.w);
      *(bf16x8*)&As[ra][ca] = p0.v;
      *(bf16x8*)&As[ra][ca + 8] = p1.v;
#pragma unroll
      for (int w3 = 0; w3 < 3; ++w3) {
        *(bf16x8*)&Bs[w3][ra][ca] = wr[w3][0];
        *(bf16x8*)&Bs[w3][ra][ca + 8] = wr[w3][1];
      }
    }
    if (k0 + 64 < H) {  // prefetch next k-tile into regs (overlaps MFMA below)
      const float4* xs = xsrc + (size_t)((k0 >> 6) + 1) * 16;
      xr0 = xs[0]; xr1 = xs[1]; xr2 = xs[2]; xr3 = xs[3];
#pragma unroll
      for (int w3 = 0; w3 < 3; ++w3) {
        const bf16x8* s2 =
            (const bf16x8*)(Wt + (size_t)w3 * (D * H) + (size_t)ra * H + k0 + 64 + ca);
        wr[w3][0] = s2[0];
        wr[w3][1] = s2[1];
      }
    }
    __syncthreads();
#pragma unroll
    for (int kk = 0; kk < 2; ++kk) {
      bf16x8 a[4];
#pragma unroll
      for (int mt = 0; mt < 4; ++mt)
        a[mt] = *(const bf16x8*)&As[mt * 16 + l15][kk * 32 + quad * 8];
#pragma unroll
      for (int nt = 0; nt < 3; ++nt) {
        const int gnt = wv * 3 + nt;
        bf16x8 b = *(const bf16x8*)&Bs[gnt >> 2][(gnt & 3) * 16 + l15][kk * 32 + quad * 8];
#pragma unroll
        for (int mt = 0; mt < 4; ++mt) acc[mt][nt] = MFMA(a[mt], b, acc[mt][nt]);
      }
    }
  }

  // epilogue: row = mbase + mt*16 + quad*4 + r; col tile gnt = wv*3+nt
#pragma unroll
  for (int nt = 0; nt < 3; ++nt) {
    const int gnt = wv * 3 + nt;
    const int w3 = gnt >> 2;
    const int d = (gnt & 3) * 16 + l15;
#pragma unroll
    for (int mt = 0; mt < 4; ++mt) {
      const int row0 = mbase + mt * 16 + quad * 4;
      const unsigned u01 = cvt2(acc[mt][nt][0], acc[mt][nt][1]);
      const unsigned u23 = cvt2(acc[mt][nt][2], acc[mt][nt][3]);
      if (w3 < 2) {
        short* dst = (w3 == 0) ? qb : kb;
        dst[(size_t)(row0 + 0) * D + d] = (short)(u01 & 0xFFFFu);
        dst[(size_t)(row0 + 1) * D + d] = (short)(u01 >> 16);
        dst[(size_t)(row0 + 2) * D + d] = (short)(u23 & 0xFFFFu);
        dst[(size_t)(row0 + 3) * D + d] = (short)(u23 >> 16);
      } else {
        const int bb = row0 >> 11, t0 = row0 & 2047;
        *(int2*)(vT + ((size_t)(bb * D + d)) * T + t0) = make_int2((int)u01, (int)u23);
      }
    }
  }
}

// ---------------------------------------------------------------------------
// Kernel 3: transposed flash attention, split-K, whole-chunk staging
// (round-3 verified loop). Chunk = CH=8 k-tiles (512 keys), staged in
// 3-tile groups (3/3/2; ONE barrier pair per group).
// mode 1: grid 640 (8 b x 80 (qt,chunk)); mode 0: fallback, grid 256.
// ---------------------------------------------------------------------------
__global__ __launch_bounds__(256) void attn_mfma(
    const short* __restrict__ qbuf, const short* __restrict__ kbuf,
    const short* __restrict__ vT, float* __restrict__ out,
    float* __restrict__ Opart, float* __restrict__ lpart, int mode) {
  __shared__ short Ks[192][72];   // 27648 B
  __shared__ short Vs[64][200];   // 25600 B  (total 53248 < 64 KB static cap)

  const int g = blockIdx.x;
  int b, qt, c;
  if (mode == 0) {
    b = g >> 5; qt = g & 31; c = 0;
  } else {
    b = g / 80;
    int r = g - b * 80;
    qt = 0; c = 0;
    // qt-groups of 8 (gg = qt/8): 8 qts x (gg+1) chunks each; totals 8+16+24+32
    for (int gg = 0;; ++gg) {
      const int cnt = 8 * (gg + 1);
      if (r < cnt) { qt = 8 * gg + r / (gg + 1); c = r - (r / (gg + 1)) * (gg + 1); break; }
      r -= cnt;
    }
  }
  const int kt0 = c * CH;
  const int kt1 = (mode == 0) ? (qt + 1) : min(kt0 + CH, qt + 1);

  const int tid = threadIdx.x;
  const int lane = tid & 63, wv = tid >> 6;
  const int l15 = lane & 15, quad = lane >> 4;
  const int qrow = qt * 64 + wv * 16 + l15;

  const short* qp = qbuf + (size_t)(b * T + qrow) * D;
  bf16x8 qf0 = *(const bf16x8*)(qp + quad * 8);
  bf16x8 qf1 = *(const bf16x8*)(qp + 32 + quad * 8);

  const int srow = tid >> 2, soff = (tid & 3) * 16;
  const short* kbb = kbuf + (size_t)b * T * D;
  const short* vbb = vT + (size_t)b * D * T;

  f32x4 o[4] = {};
  f32x4 lsum4 = {};

  for (int base = kt0; base < kt1; base += 3) {
    const int nt3 = min(3, kt1 - base);
    if (base > kt0) __syncthreads();  // prev 3-tile group fully consumed
    for (int t3 = 0; t3 < nt3; ++t3) {
      const bf16x8* kp = (const bf16x8*)(kbb + (size_t)((base + t3) * 64 + srow) * D + soff);
      bf16x8 k0 = kp[0], k1 = kp[1];
      const bf16x8* vp = (const bf16x8*)(vbb + (size_t)srow * T + (base + t3) * 64 + soff);
      bf16x8 v0 = vp[0], v1 = vp[1];
      *(bf16x8*)&Ks[t3 * 64 + srow][soff] = k0;
      *(bf16x8*)&Ks[t3 * 64 + srow][soff + 8] = k1;
      *(bf16x8*)&Vs[srow][t3 * 64 + soff] = v0;
      *(bf16x8*)&Vs[srow][t3 * 64 + soff + 8] = v1;
    }
    __syncthreads();

    for (int tt = 0; tt < nt3; ++tt) {
      const int kt = base + tt;
      // S^T = K Q^T (log2 domain: q pre-scaled by 0.125*log2e)
      f32x4 s[4] = {};
#pragma unroll
      for (int nt = 0; nt < 4; ++nt) {
        bf16x8 ka0 = *(const bf16x8*)&Ks[tt * 64 + nt * 16 + l15][quad * 8];
        bf16x8 ka1 = *(const bf16x8*)&Ks[tt * 64 + nt * 16 + l15][32 + quad * 8];
        s[nt] = MFMA(ka1, qf1, MFMA(ka0, qf0, s[nt]));
      }
      const bool diag = (kt == qt);
#pragma unroll
      for (int nt = 0; nt < 4; ++nt) {
#pragma unroll
        for (int r = 0; r < 4; ++r) {
          float p = EXP2(s[nt][r]);
          if (diag) {
            int key = kt * 64 + nt * 16 + quad * 4 + r;
            if (key > qrow) p = 0.f;
          }
          s[nt][r] = p;
        }
        lsum4 += s[nt];
      }
#if HAVE_MFMA16
      // P^T already sits in the 16x16x16 B-operand layout: pack and go.
#pragma unroll
      for (int nt = 0; nt < 4; ++nt) {
        union { unsigned u[2]; bf16x4 v; } pb;
        pb.u[0] = cvt2(s[nt][0], s[nt][1]);
        pb.u[1] = cvt2(s[nt][2], s[nt][3]);
#pragma unroll
        for (int dt = 0; dt < 4; ++dt) {
          bf16x4 va = *(const bf16x4*)&Vs[dt * 16 + l15][tt * 64 + nt * 16 + quad * 4];
          o[dt] = MFMA16(va, pb.v, o[dt]);
        }
      }
#else
      // In-wave shuffle gather of 16x16x32 B-frags (verified earlier).
#pragma unroll
      for (int h = 0; h < 2; ++h) {
        int a01 = (int)cvt2(s[2 * h][0], s[2 * h][1]);
        int a23 = (int)cvt2(s[2 * h][2], s[2 * h][3]);
        int b01 = (int)cvt2(s[2 * h + 1][0], s[2 * h + 1][1]);
        int b23 = (int)cvt2(s[2 * h + 1][2], s[2 * h + 1][3]);
        const int srcA = l15 + ((quad & 1) << 5);
        const int srcB = srcA + 16;
        int gA01 = __shfl(a01, srcA), gA01b = __shfl(b01, srcA);
        int gA23 = __shfl(a23, srcA), gA23b = __shfl(b23, srcA);
        int gB01 = __shfl(a01, srcB), gB01b = __shfl(b01, srcB);
        int gB23 = __shfl(a23, srcB), gB23b = __shfl(b23, srcB);
        union { int d[4]; bf16x8 v; } pf;
        const bool lo = (quad < 2);
        pf.d[0] = lo ? gA01 : gA01b;
        pf.d[1] = lo ? gA23 : gA23b;
        pf.d[2] = lo ? gB01 : gB01b;
        pf.d[3] = lo ? gB23 : gB23b;
#pragma unroll
        for (int dt = 0; dt < 4; ++dt) {
          bf16x8 va = *(const bf16x8*)&Vs[dt * 16 + l15][tt * 64 + h * 32 + quad * 8];
          o[dt] = MFMA(va, pf.v, o[dt]);
        }
      }
#endif
    }
  }

  float lv = (lsum4[0] + lsum4[1]) + (lsum4[2] + lsum4[3]);
  lv += __shfl_xor(lv, 16);
  lv += __shfl_xor(lv, 32);

  if (kt0 == 0 && kt1 == qt + 1) {  // sole chunk: normalize, write out
    const float inv = 1.0f / lv;
    float* op = out + (size_t)(b * T + qrow) * D;
#pragma unroll
    for (int dt = 0; dt < 4; ++dt)
      *(float4*)(op + dt * 16 + quad * 4) =
          make_float4(o[dt][0] * inv, o[dt][1] * inv, o[dt][2] * inv, o[dt][3] * inv);
  } else {
    const int prow = b * T + qrow;
    float* pp = Opart + ((size_t)c * 16384 + prow) * D;
#pragma unroll
    for (int dt = 0; dt < 4; ++dt)
      *(float4*)(pp + dt * 16 + quad * 4) =
          make_float4(o[dt][0], o[dt][1], o[dt][2], o[dt][3]);
    if (quad == 0) lpart[c * 16384 + prow] = lv;
  }
}

// ---------------------------------------------------------------------------
// Kernel 4: combine split-K partials for rows with >=2 chunks (qrow >= 512).
// 8 b x 1536 rows x 16 thr = 196,608 threads = 768 blocks.
// ---------------------------------------------------------------------------
__global__ __launch_bounds__(256) void combine_k(
    const float* __restrict__ Opart, const float* __restrict__ lpart,
    float* __restrict__ out) {
  const int gid = blockIdx.x * 256 + threadIdx.x;  // 768*256 = 196608
  const int r16 = gid >> 4;                        // 0..12287
  const int b = r16 / 1536;
  const int qrow = 512 + (r16 - b * 1536);
  const int row = b * T + qrow;
  const int d4 = (gid & 15) << 2;
  const int nc = (qrow >> 6) / CH + 1;  // 2..4 chunks
  float a0 = 0.f, a1 = 0.f, a2 = 0.f, a3 = 0.f, l = 0.f;
  for (int c = 0; c < nc; ++c) {
    const float4 t = *(const float4*)(Opart + ((size_t)c * 16384 + row) * D + d4);
    a0 += t.x; a1 += t.y; a2 += t.z; a3 += t.w;
    l += lpart[c * 16384 + row];
  }
  const float inv = 1.0f / l;
  *(float4*)(out + (size_t)row * D + d4) = make_float4(a0 * inv, a1 * inv, a2 * inv, a3 * inv);
}

// ---------------------------------------------------------------------------
extern "C" void kernel_launch(void* const* d_in, const int* in_sizes, int n_in,
                              void* d_out, int out_size, void* d_ws, size_t ws_size,
                              hipStream_t stream) {
  const float* x  = (const float*)d_in[0];
  const float* Wk = (const float*)d_in[1];
  const float* Wq = (const float*)d_in[2];
  const float* Wv = (const float*)d_in[3];
  float* out = (float*)d_out;

  const size_t M = (size_t)BATCH * T * D;  // 1,048,576 elements
  short* qb = (short*)d_ws;
  short* kb = qb + M;
  short* vT = kb + M;
  short* Wt = vT + M;                       // 196,608 shorts
  float* Opart = (float*)(Wt + 196608);
  float* lpart = Opart + (size_t)NCHUNK_MAX * 16384 * 64;

  const size_t need = (3 * M + 196608) * 2 +
                      ((size_t)NCHUNK_MAX * 16384 * 64 + (size_t)NCHUNK_MAX * 16384) * 4;
  const bool split = ws_size >= need;

  prep_w<<<dim3(16, 3), 256, 0, stream>>>(Wq, Wk, Wv, Wt);
  proj_mfma<<<dim3(256), 256, 0, stream>>>(x, Wt, qb, kb, vT);
  if (split) {
    attn_mfma<<<dim3(640), 256, 0, stream>>>(qb, kb, vT, out, Opart, lpart, 1);
    combine_k<<<dim3(768), 256, 0, stream>>>(Opart, lpart, out);
  } else {
    attn_mfma<<<dim3(256), 256, 0, stream>>>(qb, kb, vT, out, Opart, lpart, 0);
  }
}

// Round 9
// 135.928 us; speedup vs baseline: 1.8521x; 1.0002x over previous
//
#include <hip/hip_runtime.h>
#include <math.h>

#define BATCH 8
#define T 2048
#define H 1024
#define D 64

typedef __attribute__((ext_vector_type(8))) short bf16x8;
typedef __attribute__((ext_vector_type(4))) short bf16x4;
typedef __attribute__((ext_vector_type(4))) float f32x4;

// Scalar conversion (RNE), kept for prep_w.
__device__ __forceinline__ short f2bf(float f) {
  union { float f; unsigned u; } x; x.f = f;
  return (short)((x.u + 0x7FFFu + ((x.u >> 16) & 1u)) >> 16);
}

// Pair conversion, BIT-EXACT RNE (same math as f2bf), packed with v_perm.
// NOTE: v_cvt_pk_bf16_f32 is NOT used: it rounds toward zero (pkrtz
// heritage); the downward bias compounded to absmax 0.123 in round 1.
__device__ __forceinline__ unsigned cvt2(float lo, float hi) {
  union { float f; unsigned u; } a, b;
  a.f = lo; b.f = hi;
  unsigned ul = a.u + 0x7FFFu + ((a.u >> 16) & 1u);
  unsigned uh = b.u + 0x7FFFu + ((b.u >> 16) & 1u);
#if __has_builtin(__builtin_amdgcn_perm)
  return __builtin_amdgcn_perm(uh, ul, 0x07060302u);  // [ul.b2,ul.b3,uh.b2,uh.b3]
#else
  return (uh & 0xFFFF0000u) | (ul >> 16);
#endif
}

#if __has_builtin(__builtin_amdgcn_exp2f)
#define EXP2(x) __builtin_amdgcn_exp2f(x)
#else
#define EXP2(x) exp2f(x)
#endif

#define MFMA(a, b, c) __builtin_amdgcn_mfma_f32_16x16x32_bf16(a, b, c, 0, 0, 0)

#if __has_builtin(__builtin_amdgcn_mfma_f32_16x16x16bf16_1k)
#define MFMA16(a, b, c) __builtin_amdgcn_mfma_f32_16x16x16bf16_1k(a, b, c, 0, 0, 0)
#define HAVE_MFMA16 1
#elif __has_builtin(__builtin_amdgcn_mfma_f32_16x16x16_bf16)
#define MFMA16(a, b, c) __builtin_amdgcn_mfma_f32_16x16x16_bf16(a, b, c, 0, 0, 0)
#define HAVE_MFMA16 1
#else
#define HAVE_MFMA16 0
#endif

// CH=8: attn grid = 640 blocks <= 768 co-residency slots -> ONE dispatch
// wave (verified R8: 137.6 -> 136.0).
#define CH 8
#define NCHUNK_MAX 4  // ceil(32/CH)

// ---------------------------------------------------------------------------
// Kernel 1: W [1024][64] fp32 -> Wt[3][64 n][1024 k] bf16 (transposed).
// which 0 = Wq (pre-scaled by 0.125*log2e so attention uses exp2 directly).
// ---------------------------------------------------------------------------
__global__ __launch_bounds__(256) void prep_w(
    const float* __restrict__ Wq, const float* __restrict__ Wk,
    const float* __restrict__ Wv, short* __restrict__ Wt) {
  const int which = blockIdx.y;
  const float* W = which == 0 ? Wq : which == 1 ? Wk : Wv;
  const float scale = which == 0 ? 0.125f * 1.44269504088896340736f : 1.0f;
  const int kbase = blockIdx.x * 64;
  const int n = threadIdx.x & 63;
  const int k0 = threadIdx.x >> 6;
  short* dst = Wt + (size_t)which * (D * H);
#pragma unroll
  for (int i = 0; i < 16; ++i) {
    int k = kbase + i * 4 + k0;
    dst[n * H + k] = f2bf(W[(size_t)k * D + n] * scale);
  }
}

// ---------------------------------------------------------------------------
// Kernel 2: fused q/k/v projection GEMM, 64-row M-tile (round-3 verified).
// Wave tile = 64 rows x 48 cols; register-prefetch double buffering.
// ---------------------------------------------------------------------------
__global__ __launch_bounds__(256) void proj_mfma(
    const float* __restrict__ x, const short* __restrict__ Wt,
    short* __restrict__ qb, short* __restrict__ kb, short* __restrict__ vT) {
  __shared__ short As[64][72];
  __shared__ short Bs[3][64][72];
  const int mbase = blockIdx.x * 64;
  const int tid = threadIdx.x;
  const int lane = tid & 63, wv = tid >> 6;
  const int l15 = lane & 15, quad = lane >> 4;
  const int ra = tid >> 2, ca = (tid & 3) * 16;

  const float4* xsrc = (const float4*)(x + (size_t)(mbase + ra) * H + ca);
  float4 xr0 = xsrc[0], xr1 = xsrc[1], xr2 = xsrc[2], xr3 = xsrc[3];
  bf16x8 wr[3][2];
#pragma unroll
  for (int w3 = 0; w3 < 3; ++w3) {
    const bf16x8* s2 = (const bf16x8*)(Wt + (size_t)w3 * (D * H) + (size_t)ra * H + ca);
    wr[w3][0] = s2[0];
    wr[w3][1] = s2[1];
  }

  f32x4 acc[4][3] = {};  // [m-tile][n-tile]

  for (int k0 = 0; k0 < H; k0 += 64) {
    if (k0) __syncthreads();
    {
      union { unsigned u[4]; bf16x8 v; } p0, p1;
      p0.u[0] = cvt2(xr0.x, xr0.y); p0.u[1] = cvt2(xr0.z, xr0.w);
      p0.u[2] = cvt2(xr1.x, xr1.y); p0.u[3] = cvt2(xr1.z, xr1.w);
      p1.u[0] = cvt2(xr2.x, xr2.y); p1.u[1] = cvt2(xr2.z, xr2.w);
      p1.u[2] = cvt2(xr3.x, xr3.y); p1.u[3] = cvt2(xr3.z, xr3.w);
      *(bf16x8*)&As[ra][ca] = p0.v;
      *(bf16x8*)&As[ra][ca + 8] = p1.v;
#pragma unroll
      for (int w3 = 0; w3 < 3; ++w3) {
        *(bf16x8*)&Bs[w3][ra][ca] = wr[w3][0];
        *(bf16x8*)&Bs[w3][ra][ca + 8] = wr[w3][1];
      }
    }
    if (k0 + 64 < H) {  // prefetch next k-tile into regs (overlaps MFMA below)
      const float4* xs = xsrc + (size_t)((k0 >> 6) + 1) * 16;
      xr0 = xs[0]; xr1 = xs[1]; xr2 = xs[2]; xr3 = xs[3];
#pragma unroll
      for (int w3 = 0; w3 < 3; ++w3) {
        const bf16x8* s2 =
            (const bf16x8*)(Wt + (size_t)w3 * (D * H) + (size_t)ra * H + k0 + 64 + ca);
        wr[w3][0] = s2[0];
        wr[w3][1] = s2[1];
      }
    }
    __syncthreads();
#pragma unroll
    for (int kk = 0; kk < 2; ++kk) {
      bf16x8 a[4];
#pragma unroll
      for (int mt = 0; mt < 4; ++mt)
        a[mt] = *(const bf16x8*)&As[mt * 16 + l15][kk * 32 + quad * 8];
#pragma unroll
      for (int nt = 0; nt < 3; ++nt) {
        const int gnt = wv * 3 + nt;
        bf16x8 b = *(const bf16x8*)&Bs[gnt >> 2][(gnt & 3) * 16 + l15][kk * 32 + quad * 8];
#pragma unroll
        for (int mt = 0; mt < 4; ++mt) acc[mt][nt] = MFMA(a[mt], b, acc[mt][nt]);
      }
    }
  }

  // epilogue: row = mbase + mt*16 + quad*4 + r; col tile gnt = wv*3+nt
#pragma unroll
  for (int nt = 0; nt < 3; ++nt) {
    const int gnt = wv * 3 + nt;
    const int w3 = gnt >> 2;
    const int d = (gnt & 3) * 16 + l15;
#pragma unroll
    for (int mt = 0; mt < 4; ++mt) {
      const int row0 = mbase + mt * 16 + quad * 4;
      const unsigned u01 = cvt2(acc[mt][nt][0], acc[mt][nt][1]);
      const unsigned u23 = cvt2(acc[mt][nt][2], acc[mt][nt][3]);
      if (w3 < 2) {
        short* dst = (w3 == 0) ? qb : kb;
        dst[(size_t)(row0 + 0) * D + d] = (short)(u01 & 0xFFFFu);
        dst[(size_t)(row0 + 1) * D + d] = (short)(u01 >> 16);
        dst[(size_t)(row0 + 2) * D + d] = (short)(u23 & 0xFFFFu);
        dst[(size_t)(row0 + 3) * D + d] = (short)(u23 >> 16);
      } else {
        const int bb = row0 >> 11, t0 = row0 & 2047;
        *(int2*)(vT + ((size_t)(bb * D + d)) * T + t0) = make_int2((int)u01, (int)u23);
      }
    }
  }
}

// ---------------------------------------------------------------------------
// Kernel 3: transposed flash attention, split-K, whole-chunk staging
// (round-3 verified loop). Chunk = CH=8 k-tiles (512 keys), staged in
// 3-tile groups (3/3/2; ONE barrier pair per group).
// XCD-aware mapping (T1): b = g & 7 puts each batch's K/V stream on ONE
// XCD's L2 (~768 KB/batch vs 6 MB for all batches; R6 profile showed 22 MB
// attn FETCH vs ~6 MB ideal = L2 thrash with the old b = g/80 mapping).
// mode 1: grid 640 (80 r x 8 b); mode 0: fallback, grid 256.
// ---------------------------------------------------------------------------
__global__ __launch_bounds__(256) void attn_mfma(
    const short* __restrict__ qbuf, const short* __restrict__ kbuf,
    const short* __restrict__ vT, float* __restrict__ out,
    float* __restrict__ Opart, float* __restrict__ lpart, int mode) {
  __shared__ short Ks[192][72];   // 27648 B
  __shared__ short Vs[64][200];   // 25600 B  (total 53248 < 64 KB static cap)

  const int g = blockIdx.x;
  int b, qt, c;
  if (mode == 0) {
    b = g >> 5; qt = g & 31; c = 0;
  } else {
    b = g & 7;          // XCD-aligned: same batch -> same XCD's L2
    int r = g >> 3;     // 0..79
    qt = 0; c = 0;
    // qt-groups of 8 (gg = qt/8): 8 qts x (gg+1) chunks each; totals 8+16+24+32
    for (int gg = 0;; ++gg) {
      const int cnt = 8 * (gg + 1);
      if (r < cnt) { qt = 8 * gg + r / (gg + 1); c = r - (r / (gg + 1)) * (gg + 1); break; }
      r -= cnt;
    }
  }
  const int kt0 = c * CH;
  const int kt1 = (mode == 0) ? (qt + 1) : min(kt0 + CH, qt + 1);

  const int tid = threadIdx.x;
  const int lane = tid & 63, wv = tid >> 6;
  const int l15 = lane & 15, quad = lane >> 4;
  const int qrow = qt * 64 + wv * 16 + l15;

  const short* qp = qbuf + (size_t)(b * T + qrow) * D;
  bf16x8 qf0 = *(const bf16x8*)(qp + quad * 8);
  bf16x8 qf1 = *(const bf16x8*)(qp + 32 + quad * 8);

  const int srow = tid >> 2, soff = (tid & 3) * 16;
  const short* kbb = kbuf + (size_t)b * T * D;
  const short* vbb = vT + (size_t)b * D * T;

  f32x4 o[4] = {};
  f32x4 lsum4 = {};

  for (int base = kt0; base < kt1; base += 3) {
    const int nt3 = min(3, kt1 - base);
    if (base > kt0) __syncthreads();  // prev 3-tile group fully consumed
    for (int t3 = 0; t3 < nt3; ++t3) {
      const bf16x8* kp = (const bf16x8*)(kbb + (size_t)((base + t3) * 64 + srow) * D + soff);
      bf16x8 k0 = kp[0], k1 = kp[1];
      const bf16x8* vp = (const bf16x8*)(vbb + (size_t)srow * T + (base + t3) * 64 + soff);
      bf16x8 v0 = vp[0], v1 = vp[1];
      *(bf16x8*)&Ks[t3 * 64 + srow][soff] = k0;
      *(bf16x8*)&Ks[t3 * 64 + srow][soff + 8] = k1;
      *(bf16x8*)&Vs[srow][t3 * 64 + soff] = v0;
      *(bf16x8*)&Vs[srow][t3 * 64 + soff + 8] = v1;
    }
    __syncthreads();

    for (int tt = 0; tt < nt3; ++tt) {
      const int kt = base + tt;
      // S^T = K Q^T (log2 domain: q pre-scaled by 0.125*log2e)
      f32x4 s[4] = {};
#pragma unroll
      for (int nt = 0; nt < 4; ++nt) {
        bf16x8 ka0 = *(const bf16x8*)&Ks[tt * 64 + nt * 16 + l15][quad * 8];
        bf16x8 ka1 = *(const bf16x8*)&Ks[tt * 64 + nt * 16 + l15][32 + quad * 8];
        s[nt] = MFMA(ka1, qf1, MFMA(ka0, qf0, s[nt]));
      }
      const bool diag = (kt == qt);
#pragma unroll
      for (int nt = 0; nt < 4; ++nt) {
#pragma unroll
        for (int r = 0; r < 4; ++r) {
          float p = EXP2(s[nt][r]);
          if (diag) {
            int key = kt * 64 + nt * 16 + quad * 4 + r;
            if (key > qrow) p = 0.f;
          }
          s[nt][r] = p;
        }
        lsum4 += s[nt];
      }
#if HAVE_MFMA16
      // P^T already sits in the 16x16x16 B-operand layout: pack and go.
#pragma unroll
      for (int nt = 0; nt < 4; ++nt) {
        union { unsigned u[2]; bf16x4 v; } pb;
        pb.u[0] = cvt2(s[nt][0], s[nt][1]);
        pb.u[1] = cvt2(s[nt][2], s[nt][3]);
#pragma unroll
        for (int dt = 0; dt < 4; ++dt) {
          bf16x4 va = *(const bf16x4*)&Vs[dt * 16 + l15][tt * 64 + nt * 16 + quad * 4];
          o[dt] = MFMA16(va, pb.v, o[dt]);
        }
      }
#else
      // In-wave shuffle gather of 16x16x32 B-frags (verified earlier).
#pragma unroll
      for (int h = 0; h < 2; ++h) {
        int a01 = (int)cvt2(s[2 * h][0], s[2 * h][1]);
        int a23 = (int)cvt2(s[2 * h][2], s[2 * h][3]);
        int b01 = (int)cvt2(s[2 * h + 1][0], s[2 * h + 1][1]);
        int b23 = (int)cvt2(s[2 * h + 1][2], s[2 * h + 1][3]);
        const int srcA = l15 + ((quad & 1) << 5);
        const int srcB = srcA + 16;
        int gA01 = __shfl(a01, srcA), gA01b = __shfl(b01, srcA);
        int gA23 = __shfl(a23, srcA), gA23b = __shfl(b23, srcA);
        int gB01 = __shfl(a01, srcB), gB01b = __shfl(b01, srcB);
        int gB23 = __shfl(a23, srcB), gB23b = __shfl(b23, srcB);
        union { int d[4]; bf16x8 v; } pf;
        const bool lo = (quad < 2);
        pf.d[0] = lo ? gA01 : gA01b;
        pf.d[1] = lo ? gA23 : gA23b;
        pf.d[2] = lo ? gB01 : gB01b;
        pf.d[3] = lo ? gB23 : gB23b;
#pragma unroll
        for (int dt = 0; dt < 4; ++dt) {
          bf16x8 va = *(const bf16x8*)&Vs[dt * 16 + l15][tt * 64 + h * 32 + quad * 8];
          o[dt] = MFMA(va, pf.v, o[dt]);
        }
      }
#endif
    }
  }

  float lv = (lsum4[0] + lsum4[1]) + (lsum4[2] + lsum4[3]);
  lv += __shfl_xor(lv, 16);
  lv += __shfl_xor(lv, 32);

  if (kt0 == 0 && kt1 == qt + 1) {  // sole chunk: normalize, write out
    const float inv = 1.0f / lv;
    float* op = out + (size_t)(b * T + qrow) * D;
#pragma unroll
    for (int dt = 0; dt < 4; ++dt)
      *(float4*)(op + dt * 16 + quad * 4) =
          make_float4(o[dt][0] * inv, o[dt][1] * inv, o[dt][2] * inv, o[dt][3] * inv);
  } else {
    const int prow = b * T + qrow;
    float* pp = Opart + ((size_t)c * 16384 + prow) * D;
#pragma unroll
    for (int dt = 0; dt < 4; ++dt)
      *(float4*)(pp + dt * 16 + quad * 4) =
          make_float4(o[dt][0], o[dt][1], o[dt][2], o[dt][3]);
    if (quad == 0) lpart[c * 16384 + prow] = lv;
  }
}

// ---------------------------------------------------------------------------
// Kernel 4: combine split-K partials for rows with >=2 chunks (qrow >= 512).
// 8 b x 1536 rows x 16 thr = 196,608 threads = 768 blocks.
// ---------------------------------------------------------------------------
__global__ __launch_bounds__(256) void combine_k(
    const float* __restrict__ Opart, const float* __restrict__ lpart,
    float* __restrict__ out) {
  const int gid = blockIdx.x * 256 + threadIdx.x;  // 768*256 = 196608
  const int r16 = gid >> 4;                        // 0..12287
  const int b = r16 / 1536;
  const int qrow = 512 + (r16 - b * 1536);
  const int row = b * T + qrow;
  const int d4 = (gid & 15) << 2;
  const int nc = (qrow >> 6) / CH + 1;  // 2..4 chunks
  float a0 = 0.f, a1 = 0.f, a2 = 0.f, a3 = 0.f, l = 0.f;
  for (int c = 0; c < nc; ++c) {
    const float4 t = *(const float4*)(Opart + ((size_t)c * 16384 + row) * D + d4);
    a0 += t.x; a1 += t.y; a2 += t.z; a3 += t.w;
    l += lpart[c * 16384 + row];
  }
  const float inv = 1.0f / l;
  *(float4*)(out + (size_t)row * D + d4) = make_float4(a0 * inv, a1 * inv, a2 * inv, a3 * inv);
}

// ---------------------------------------------------------------------------
extern "C" void kernel_launch(void* const* d_in, const int* in_sizes, int n_in,
                              void* d_out, int out_size, void* d_ws, size_t ws_size,
                              hipStream_t stream) {
  const float* x  = (const float*)d_in[0];
  const float* Wk = (const float*)d_in[1];
  const float* Wq = (const float*)d_in[2];
  const float* Wv = (const float*)d_in[3];
  float* out = (float*)d_out;

  const size_t M = (size_t)BATCH * T * D;  // 1,048,576 elements
  short* qb = (short*)d_ws;
  short* kb = qb + M;
  short* vT = kb + M;
  short* Wt = vT + M;                       // 196,608 shorts
  float* Opart = (float*)(Wt + 196608);
  float* lpart = Opart + (size_t)NCHUNK_MAX * 16384 * 64;

  const size_t need = (3 * M + 196608) * 2 +
                      ((size_t)NCHUNK_MAX * 16384 * 64 + (size_t)NCHUNK_MAX * 16384) * 4;
  const bool split = ws_size >= need;

  prep_w<<<dim3(16, 3), 256, 0, stream>>>(Wq, Wk, Wv, Wt);
  proj_mfma<<<dim3(256), 256, 0, stream>>>(x, Wt, qb, kb, vT);
  if (split) {
    attn_mfma<<<dim3(640), 256, 0, stream>>>(qb, kb, vT, out, Opart, lpart, 1);
    combine_k<<<dim3(768), 256, 0, stream>>>(Opart, lpart, out);
  } else {
    attn_mfma<<<dim3(256), 256, 0, stream>>>(qb, kb, vT, out, Opart, lpart, 0);
  }
}